// Round 7
// baseline (575.232 us; speedup 1.0000x reference)
//
#include <hip/hip_runtime.h>
#include <hip/hip_bf16.h>
#include <cstdint>

// ---------------- problem constants ----------------
constexpr int kB  = 32;
constexpr int kC  = 1024;
constexpr int kH  = 48;
constexpr int kW  = 24;
constexpr int kP  = 3;
constexpr int kPH = 16;
constexpr int kN  = kPH * kW;          // 384
constexpr int kHW = kH * kW;           // 1152
constexpr int64_t kCHW = (int64_t)kC * kHW;

typedef __attribute__((ext_vector_type(8))) short short8b;   // bf16x8 frag
typedef __attribute__((ext_vector_type(4))) float f32x4;

__device__ __forceinline__ void gl_lds16(const void* g, void* l) {
    __builtin_amdgcn_global_load_lds(
        (const __attribute__((address_space(1))) void*)g,
        (__attribute__((address_space(3))) void*)l, 16, 0, 0);
}

// XCD pair-locality swizzle (identity unless gridDim.z % 8 == 0).
__device__ __forceinline__ void swz_block(int& bx, int& by, int& bz) {
    const int gx = gridDim.x, gy = gridDim.y, gz = gridDim.z;
    if ((gz & 7) == 0) {
        const int tpp = gx * gy;
        const int L   = (blockIdx.z * gy + blockIdx.y) * gx + blockIdx.x;
        const int xcd = L & 7;
        const int idx = L >> 3;
        const int ppx = gz >> 3;
        const int pairL = idx / tpp;
        const int tile  = idx - pairL * tpp;
        bz = xcd * ppx + pairL;
        by = tile / gx;
        bx = tile - by * gx;
    } else {
        bx = blockIdx.x; by = blockIdx.y; bz = blockIdx.z;
    }
}

#define WAIT0()       asm volatile("s_waitcnt vmcnt(0)" ::: "memory")
#define RAW_BARRIER() asm volatile("s_barrier" ::: "memory")
#define SFENCE()      __builtin_amdgcn_sched_barrier(0)

// ---------------- gate + bqk stack ----------------
__global__ void gate_kernel(const int* __restrict__ modality,
                            const float* __restrict__ gW1, const float* __restrict__ gb1,
                            const float* __restrict__ gW2, const float* __restrict__ gb2,
                            const float* __restrict__ gpa, const float* __restrict__ gca,
                            const float* __restrict__ bq, const float* __restrict__ bk,
                            float* __restrict__ wg, float* __restrict__ cpa,
                            float* __restrict__ cca, float* __restrict__ bqk)
{
    const int t = threadIdx.x;
    if (t < 768) {
        const int p = t >> 8, o = t & 255;
        bqk[t] = (o < 128) ? bq[p * 128 + o] : bk[p * 128 + (o - 128)];
    }
    if (t < kB * kP) {
        const int b = t / kP, p = t % kP;
        const float m = (float)modality[b];
        float acc = gb2[p];
        #pragma unroll
        for (int j = 0; j < 64; ++j) {
            float h = fmaxf(fmaf(m, gW1[j], gb1[j]), 0.0f);
            acc = fmaf(gW2[p * 64 + j], h, acc);
        }
        const float w = 1.0f / (1.0f + __expf(-acc));
        wg[t]  = w;
        cpa[t] = w * gpa[p];
        cca[t] = w * gca[p];
    }
}

// ---------------- weight precast fp32 -> bf16 ----------------
__global__ __launch_bounds__(256)
void wcast_kernel(const float* __restrict__ Wq, const float* __restrict__ Wk,
                  const float* __restrict__ Wv,
                  __hip_bfloat16* __restrict__ Wqkb, __hip_bfloat16* __restrict__ Wvb)
{
    const int64_t i = (int64_t)blockIdx.x * 256 + threadIdx.x;
    if (i < 196608) {
        const int64_t e = i * 4;
        const int p = (int)(e / 262144);
        const int rem = (int)(e % 262144);
        const int o = rem / 1024, c = rem % 1024;
        const float* s = (o < 128) ? (Wq + (int64_t)p * 131072 + (int64_t)o * 1024 + c)
                                   : (Wk + (int64_t)p * 131072 + (int64_t)(o - 128) * 1024 + c);
        float4 v = *(const float4*)s;
        __hip_bfloat16* d = Wqkb + e;
        d[0] = __float2bfloat16(v.x); d[1] = __float2bfloat16(v.y);
        d[2] = __float2bfloat16(v.z); d[3] = __float2bfloat16(v.w);
    } else if (i < 196608 + 786432) {
        const int64_t e = (i - 196608) * 4;
        float4 v = *(const float4*)(Wv + e);
        __hip_bfloat16* d = Wvb + e;
        d[0] = __float2bfloat16(v.x); d[1] = __float2bfloat16(v.y);
        d[2] = __float2bfloat16(v.z); d[3] = __float2bfloat16(v.w);
    }
}

// ---------------- Z zeroing (per chunk) ----------------
__global__ void zeroz_kernel(float* __restrict__ Z)
{
    Z[(int64_t)blockIdx.x * 1024 + threadIdx.x] = 0.0f;
}

// ---------------- per-chunk cast + transpose, vectorized (G13) -----------
__global__ __launch_bounds__(256)
void cast_tr_kernel(const float* __restrict__ x,  // + b0*kCHW
                    __hip_bfloat16* __restrict__ xfb,
                    __hip_bfloat16* __restrict__ xfT)
{
    int bx, by, bz;                 // grid (32, 3, CH)
    swz_block(bx, by, bz);
    const int j = bz;
    const int bb = j / kP, pp = j % kP;
    const float* src = x + (int64_t)bb * kCHW + pp * kN;
    const int c0 = bx * 32, n0 = by * 128;
    __shared__ float tile[32][129];
    const int tx = threadIdx.x & 31, ty = threadIdx.x >> 5;
    #pragma unroll
    for (int r = 0; r < 4; ++r) {
        const int cl = ty * 4 + r;
        const int c  = c0 + cl;
        float4 v = *(const float4*)(src + (int64_t)c * kHW + n0 + tx * 4);
        __hip_bfloat16 h0 = __float2bfloat16(v.x), h1 = __float2bfloat16(v.y);
        __hip_bfloat16 h2 = __float2bfloat16(v.z), h3 = __float2bfloat16(v.w);
        ushort4 hv;
        hv.x = *(ushort*)&h0; hv.y = *(ushort*)&h1;
        hv.z = *(ushort*)&h2; hv.w = *(ushort*)&h3;
        *(ushort4*)((ushort*)xfb + (int64_t)j * 393216 + (int64_t)c * kN + n0 + tx * 4) = hv;
        tile[cl][tx * 4 + 0] = v.x; tile[cl][tx * 4 + 1] = v.y;
        tile[cl][tx * 4 + 2] = v.z; tile[cl][tx * 4 + 3] = v.w;
    }
    __syncthreads();
    const int cc = (threadIdx.x & 15) * 2;
    const int nr = threadIdx.x >> 4;          // 0..15
    #pragma unroll
    for (int r = 0; r < 8; ++r) {
        const int nl = r * 16 + nr;
        __hip_bfloat16 h0 = __float2bfloat16(tile[cc][nl]);
        __hip_bfloat16 h1 = __float2bfloat16(tile[cc + 1][nl]);
        ushort2 h2; h2.x = *(ushort*)&h0; h2.y = *(ushort*)&h1;
        *(ushort2*)((ushort*)xfT + (int64_t)j * 393216 + (int64_t)(n0 + nl) * kC + c0 + cc) = h2;
    }
}

// ---------------- bf16 MFMA GEMM, 128x128 tile, BK=64 ---------------------
// m97/m103-proven shape: SINGLE 32KB buffer, vmcnt(0) drain, 2 barriers,
// 4 blocks/CU. Block-level TLP hides the drain (m114); all 64KB-dbuf /
// counted-vmcnt variants of rounds 0-6 sat at 2 blk/CU = the m132
// regression (508-620 TF vs m97's 874).
// C[m,n] = sum_k A[m,k]*B[n,k]. BIAS: 0 none, 2 col bias.
template<int BIAS>
__global__ __launch_bounds__(256, 4)
void mm_kernel(const __hip_bfloat16* __restrict__ A0, int64_t aSB, int64_t aSP, int lda,
               const __hip_bfloat16* __restrict__ B0, int64_t bSB, int64_t bSP, int ldb,
               __hip_bfloat16* __restrict__ C0, int64_t cSB, int64_t cSP, int ldc,
               const float* __restrict__ bias0, int biasSP, int K)
{
    __shared__ char lds[32768];   // 16KB A + 16KB B, single buffer

    int bx, by, bz;
    swz_block(bx, by, bz);
    const int j = bz, bb = j / kP, pp = j % kP;
    const char* Ab = (const char*)(A0 + (int64_t)bb * aSB + (int64_t)pp * aSP);
    const char* Bb = (const char*)(B0 + (int64_t)bb * bSB + (int64_t)pp * bSP);
    const int m0 = bx * 128, n0 = by * 128;
    const int t = threadIdx.x, lane = t & 63, wv = t >> 6;
    const int wm = (wv & 1) * 64, wn = (wv >> 1) * 64;
    const size_t ldab = (size_t)lda * 2, ldbb = (size_t)ldb * 2;

    const int rr   = wv * 8 + (lane >> 3);
    const int gsrc = ((lane & 7) ^ (lane >> 3)) * 16;
    const int lrow = (wv * 8 + (lane >> 3)) * 128 + (lane & 7) * 16;

    auto STAGE = [&](int k0) {
        const char* Asrc = Ab + (size_t)(m0 + rr) * ldab + (size_t)k0 * 2 + gsrc;
        const char* Bsrc = Bb + (size_t)(n0 + rr) * ldbb + (size_t)k0 * 2 + gsrc;
        char* As = lds;
        char* Bs = As + 16384;
        #pragma unroll
        for (int i = 0; i < 4; ++i) {
            gl_lds16(Asrc + (size_t)i * 32 * ldab, As + i * 4096 + lrow);
            gl_lds16(Bsrc + (size_t)i * 32 * ldbb, Bs + i * 4096 + lrow);
        }
    };

    f32x4 acc[4][4];
    #pragma unroll
    for (int a = 0; a < 4; ++a)
        #pragma unroll
        for (int b = 0; b < 4; ++b) acc[a][b] = (f32x4){0.f, 0.f, 0.f, 0.f};

    const int nk = K >> 6;
    for (int k = 0; k < nk; ++k) {
        STAGE(k << 6);
        WAIT0();
        SFENCE();
        RAW_BARRIER();
        const char* As = lds;
        const char* Bs = As + 16384;
        #pragma unroll
        for (int kk = 0; kk < 2; ++kk) {
            const int gpos = ((kk * 4 + (lane >> 4)) ^ (lane & 7)) * 16;
            short8b af[4], bf[4];
            #pragma unroll
            for (int f = 0; f < 4; ++f) {
                af[f] = *(const short8b*)(As + (wm + f * 16 + (lane & 15)) * 128 + gpos);
                bf[f] = *(const short8b*)(Bs + (wn + f * 16 + (lane & 15)) * 128 + gpos);
            }
            #pragma unroll
            for (int fm = 0; fm < 4; ++fm)
                #pragma unroll
                for (int fn = 0; fn < 4; ++fn)
                    acc[fm][fn] = __builtin_amdgcn_mfma_f32_16x16x32_bf16(
                        af[fm], bf[fn], acc[fm][fn], 0, 0, 0);
        }
        RAW_BARRIER();
    }

    __hip_bfloat16* Cm = C0 + (int64_t)bb * cSB + (int64_t)pp * cSP;
    #pragma unroll
    for (int fn = 0; fn < 4; ++fn) {
        const int col = n0 + wn + fn * 16 + (lane & 15);
        const float cb = (BIAS == 2) ? bias0[pp * biasSP + col] : 0.0f;
        #pragma unroll
        for (int fm = 0; fm < 4; ++fm)
            #pragma unroll
            for (int jr = 0; jr < 4; ++jr) {
                const int row = m0 + wm + fm * 16 + (lane >> 4) * 4 + jr;
                Cm[(int64_t)row * ldc + col] = __float2bfloat16(acc[fm][fn][jr] + cb);
            }
    }
}

// ---------------- triangular e-GEMM with fused exp + Z atomics ------------
// Same m97-style single-buffer conversion.
__global__ __launch_bounds__(256, 4)
void ecam_kernel(const __hip_bfloat16* __restrict__ xfb,   // [CH][1024][384]
                 __hip_bfloat16* __restrict__ eb,          // [CH][1024][1024]
                 float* __restrict__ Z)                    // [CH][1024]
{
    __shared__ char lds[32768];

    int bx, by, bz;                 // grid (36, 1, CH); bx = triangle index
    swz_block(bx, by, bz);
    const int j = bz;
    int bi = 0;
    while ((bi + 1) * (bi + 2) / 2 <= bx) ++bi;   // <= 7 iters
    const int bj = bx - bi * (bi + 1) / 2;        // bi >= bj
    const char* Ab = (const char*)(xfb + (int64_t)j * 393216);
    const int m0 = bi * 128, n0 = bj * 128;
    const int t = threadIdx.x, lane = t & 63, wv = t >> 6;
    const int wm = (wv & 1) * 64, wn = (wv >> 1) * 64;
    constexpr size_t ldab = 768;   // 384 bf16

    const int rr   = wv * 8 + (lane >> 3);
    const int gsrc = ((lane & 7) ^ (lane >> 3)) * 16;
    const int lrow = (wv * 8 + (lane >> 3)) * 128 + (lane & 7) * 16;

    auto STAGE = [&](int k0) {
        const char* Asrc = Ab + (size_t)(m0 + rr) * ldab + (size_t)k0 * 2 + gsrc;
        const char* Bsrc = Ab + (size_t)(n0 + rr) * ldab + (size_t)k0 * 2 + gsrc;
        char* As = lds;
        char* Bs = As + 16384;
        #pragma unroll
        for (int i = 0; i < 4; ++i) {
            gl_lds16(Asrc + (size_t)i * 32 * ldab, As + i * 4096 + lrow);
            gl_lds16(Bsrc + (size_t)i * 32 * ldab, Bs + i * 4096 + lrow);
        }
    };

    f32x4 acc[4][4];
    #pragma unroll
    for (int a = 0; a < 4; ++a)
        #pragma unroll
        for (int b = 0; b < 4; ++b) acc[a][b] = (f32x4){0.f, 0.f, 0.f, 0.f};

    for (int k = 0; k < 6; ++k) {
        STAGE(k << 6);
        WAIT0();
        SFENCE();
        RAW_BARRIER();
        const char* As = lds;
        const char* Bs = As + 16384;
        #pragma unroll
        for (int kk = 0; kk < 2; ++kk) {
            const int gpos = ((kk * 4 + (lane >> 4)) ^ (lane & 7)) * 16;
            short8b af[4], bf[4];
            #pragma unroll
            for (int f = 0; f < 4; ++f) {
                af[f] = *(const short8b*)(As + (wm + f * 16 + (lane & 15)) * 128 + gpos);
                bf[f] = *(const short8b*)(Bs + (wn + f * 16 + (lane & 15)) * 128 + gpos);
            }
            #pragma unroll
            for (int fm = 0; fm < 4; ++fm)
                #pragma unroll
                for (int fn = 0; fn < 4; ++fn)
                    acc[fm][fn] = __builtin_amdgcn_mfma_f32_16x16x32_bf16(
                        af[fm], bf[fn], acc[fm][fn], 0, 0, 0);
        }
        RAW_BARRIER();
    }

    // transform acc -> p = exp(-60 - S) in place (literal indices only)
    #pragma unroll
    for (int fm = 0; fm < 4; ++fm)
        #pragma unroll
        for (int fn = 0; fn < 4; ++fn)
            #pragma unroll
            for (int jr = 0; jr < 4; ++jr)
                acc[fm][fn][jr] = __expf(-60.f - acc[fm][fn][jr]);

    __hip_bfloat16* Cm = eb + (int64_t)j * 1048576;
    float* Zp = Z + (int64_t)j * 1024;

    // normal tile write + row sums -> Z[row]
    #pragma unroll
    for (int fm = 0; fm < 4; ++fm)
        #pragma unroll
        for (int jr = 0; jr < 4; ++jr) {
            const int row = m0 + wm + fm * 16 + (lane >> 4) * 4 + jr;
            float v = 0.f;
            #pragma unroll
            for (int fn = 0; fn < 4; ++fn) {
                const int col = n0 + wn + fn * 16 + (lane & 15);
                Cm[(int64_t)row * 1024 + col] = __float2bfloat16(acc[fm][fn][jr]);
                v += acc[fm][fn][jr];
            }
            v += __shfl_xor(v, 1);
            v += __shfl_xor(v, 2);
            v += __shfl_xor(v, 4);
            v += __shfl_xor(v, 8);
            if ((lane & 15) == 0) atomicAdd(Zp + row, v);
        }

    if (bi != bj) {
        // mirrored tile write: Cm[col][row0..row0+3] as one 8B packed store
        #pragma unroll
        for (int fn = 0; fn < 4; ++fn) {
            const int col = n0 + wn + fn * 16 + (lane & 15);
            float v2 = 0.f;
            #pragma unroll
            for (int fm = 0; fm < 4; ++fm) {
                const int row0 = m0 + wm + fm * 16 + (lane >> 4) * 4;
                __hip_bfloat16 h0 = __float2bfloat16(acc[fm][fn][0]);
                __hip_bfloat16 h1 = __float2bfloat16(acc[fm][fn][1]);
                __hip_bfloat16 h2 = __float2bfloat16(acc[fm][fn][2]);
                __hip_bfloat16 h3 = __float2bfloat16(acc[fm][fn][3]);
                ushort4 w4;
                w4.x = *(ushort*)&h0; w4.y = *(ushort*)&h1;
                w4.z = *(ushort*)&h2; w4.w = *(ushort*)&h3;
                *(ushort4*)((ushort*)Cm + (int64_t)col * 1024 + row0) = w4;
                v2 += (acc[fm][fn][0] + acc[fm][fn][1]) +
                      (acc[fm][fn][2] + acc[fm][fn][3]);
            }
            // column sums -> Z[col] (mirror block's row sums)
            v2 += __shfl_xor(v2, 16);
            v2 += __shfl_xor(v2, 32);
            if ((lane >> 4) == 0) atomicAdd(Zp + col, v2);
        }
    }
}

// ---------------- merged final GEMM (K = 2*1024), m97-style ---------------
// acc = Ep @ xfT^T (k 0..15, BK=64); acc *= cca/Z[row]; acc += Wv@yT^T
// (k 16..31); out = x*(1+wg) + acc + cpa*bv[row].
// 128x128 tile, 4 waves, BK=64, SINGLE 32KB buffer, vmcnt(0) drain,
// 2 barriers, 4 blocks/CU (launch_bounds(256,4)). Addressing identical
// to round-0's PMC-verified conflict-free layout.
__global__ __launch_bounds__(256, 4)
void ep_cam_kernel(const __hip_bfloat16* __restrict__ Wvb,  // [P][1024][1024]
                   const __hip_bfloat16* __restrict__ yTb,  // [CH][384][1024]
                   const __hip_bfloat16* __restrict__ eb,   // [CH][1024][1024]
                   const __hip_bfloat16* __restrict__ xfT,  // [CH][384][1024]
                   const float* __restrict__ Z,             // [CH][1024]
                   const float* __restrict__ x,             // + b0*kCHW
                   float* __restrict__ out,                 // + b0*kCHW
                   const float* __restrict__ wg,            // + pair0
                   const float* __restrict__ cpa,           // + pair0
                   const float* __restrict__ cca,           // + pair0
                   const float* __restrict__ bv)            // [P][1024]
{
    __shared__ char lds[32768];     // 16KB A + 16KB B, single buffer

    int bx, by, bz;                 // grid (8, 3, CH)
    swz_block(bx, by, bz);
    const int j = bz, bb = j / kP, pp = j % kP;
    const int m0 = bx * 128, n0 = by * 128;
    const int t = threadIdx.x, lane = t & 63, wv = t >> 6;
    const int wm = (wv & 1) * 64, wn = (wv >> 1) * 64;

    const int rr   = wv * 8 + (lane >> 3);
    const int gsrc = ((lane & 7) ^ (lane >> 3)) * 16;
    const int lrow = (wv * 8 + (lane >> 3)) * 128 + (lane & 7) * 16;

    const char* AbW = (const char*)(Wvb + (int64_t)pp * 1048576);
    const char* AbE = (const char*)(eb  + (int64_t)j  * 1048576);
    const char* BbY = (const char*)(yTb + (int64_t)j * 393216);
    const char* BbX = (const char*)(xfT + (int64_t)j * 393216);

    auto STAGE = [&](int k) {        // 8 gl_lds16 per lane
        const char* A = (k < 16) ? AbE : AbW;    // half 0 = E, half 1 = Wv
        const char* B = (k < 16) ? BbX : BbY;
        const size_t k0b = (size_t)(k & 15) * 128;  // 64 bf16 = 128B per step
        const char* Asrc = A + (size_t)(m0 + rr) * 2048 + k0b + gsrc;
        const char* Bsrc = B + (size_t)(n0 + rr) * 2048 + k0b + gsrc;
        char* As = lds;
        char* Bs = As + 16384;
        #pragma unroll
        for (int i = 0; i < 4; ++i) {
            gl_lds16(Asrc + (size_t)i * 32 * 2048, As + i * 4096 + lrow);
            gl_lds16(Bsrc + (size_t)i * 32 * 2048, Bs + i * 4096 + lrow);
        }
    };

    // preload row scales so the mid-loop rescale is pure VALU
    const float cfc = cca[j];
    const float* Zp = Z + (int64_t)j * 1024;
    float zsc[4][4];
    #pragma unroll
    for (int fm = 0; fm < 4; ++fm)
        #pragma unroll
        for (int jr = 0; jr < 4; ++jr) {
            const int row = m0 + wm + fm * 16 + (lane >> 4) * 4 + jr;
            zsc[fm][jr] = cfc / Zp[row];
        }

    f32x4 acc[4][4];
    #pragma unroll
    for (int a = 0; a < 4; ++a)
        #pragma unroll
        for (int b = 0; b < 4; ++b) acc[a][b] = (f32x4){0.f, 0.f, 0.f, 0.f};

    #pragma unroll 1
    for (int k = 0; k < 32; ++k) {
        STAGE(k);
        WAIT0();
        SFENCE();
        RAW_BARRIER();
        if (k == 16) {               // fold CAM row-scale into the C operand
            #pragma unroll
            for (int fm = 0; fm < 4; ++fm)
                #pragma unroll
                for (int jr = 0; jr < 4; ++jr) {
                    const float zs = zsc[fm][jr];
                    #pragma unroll
                    for (int fn = 0; fn < 4; ++fn) acc[fm][fn][jr] *= zs;
                }
        }
        const char* As = lds;
        const char* Bs = As + 16384;
        #pragma unroll
        for (int kk = 0; kk < 2; ++kk) {
            const int gpos = ((kk * 4 + (lane >> 4)) ^ (lane & 7)) * 16;
            short8b af[4], bf[4];
            #pragma unroll
            for (int f = 0; f < 4; ++f) {
                af[f] = *(const short8b*)(As + (wm + f * 16 + (lane & 15)) * 128 + gpos);
                bf[f] = *(const short8b*)(Bs + (wn + f * 16 + (lane & 15)) * 128 + gpos);
            }
            #pragma unroll
            for (int fm = 0; fm < 4; ++fm)
                #pragma unroll
                for (int fn = 0; fn < 4; ++fn)
                    acc[fm][fn] = __builtin_amdgcn_mfma_f32_16x16x32_bf16(
                        af[fm], bf[fn], acc[fm][fn], 0, 0, 0);
        }
        RAW_BARRIER();
    }

    const float gsc = 1.0f + wg[j];
    const float cfp = cpa[j];
    const float* Xm = x   + (int64_t)bb * kCHW + pp * kN;
    float*       Om = out + (int64_t)bb * kCHW + pp * kN;
    #pragma unroll
    for (int fm = 0; fm < 4; ++fm)
        #pragma unroll
        for (int jr = 0; jr < 4; ++jr) {
            const int row = m0 + wm + fm * 16 + (lane >> 4) * 4 + jr;
            const float rb = cfp * bv[pp * 1024 + row];
            #pragma unroll
            for (int fn = 0; fn < 4; ++fn) {
                const int col = n0 + wn + fn * 16 + (lane & 15);
                const int64_t off = (int64_t)row * kHW + col;
                Om[off] = fmaf(gsc, Xm[off], acc[fm][fn][jr] + rb);
            }
        }
}

// ---------------- PAM softmax: 4 rows per 256-thr block ------------------
__global__ __launch_bounds__(256) void sm_pam(__hip_bfloat16* __restrict__ buf,
                                              const float* __restrict__ scale,
                                              int chPairs)
{
    const int R = blockIdx.x * 4 + (threadIdx.x >> 6);   // global row id
    const int pair = R / kN, row = R % kN;
    __hip_bfloat16* rp = buf + (int64_t)pair * (kN * kN) + (int64_t)row * kN;
    const int t = threadIdx.x & 63;
    float v[6];
    float mx = -3.402823466e38f;
    #pragma unroll
    for (int r = 0; r < 6; ++r) {
        v[r] = __bfloat162float(rp[t + 64 * r]);
        mx = fmaxf(mx, v[r]);
    }
    #pragma unroll
    for (int off = 32; off > 0; off >>= 1) mx = fmaxf(mx, __shfl_xor(mx, off));
    float s = 0.0f;
    #pragma unroll
    for (int r = 0; r < 6; ++r) { v[r] = __expf(v[r] - mx); s += v[r]; }
    #pragma unroll
    for (int off = 32; off > 0; off >>= 1) s += __shfl_xor(s, off);
    const float inv = scale[pair] / s;
    #pragma unroll
    for (int r = 0; r < 6; ++r) rp[t + 64 * r] = __float2bfloat16(v[r] * inv);
}

// ---------------- launch ----------------
extern "C" void kernel_launch(void* const* d_in, const int* in_sizes, int n_in,
                              void* d_out, int out_size, void* d_ws, size_t ws_size,
                              hipStream_t stream)
{
    const float* x   = (const float*)d_in[0];
    const int*   mod = (const int*)d_in[1];
    const float* Wq  = (const float*)d_in[2];
    const float* bq  = (const float*)d_in[3];
    const float* Wk  = (const float*)d_in[4];
    const float* bk  = (const float*)d_in[5];
    const float* Wv  = (const float*)d_in[6];
    const float* bv  = (const float*)d_in[7];
    const float* gpa = (const float*)d_in[8];
    const float* gca = (const float*)d_in[9];
    const float* gW1 = (const float*)d_in[10];
    const float* gb1 = (const float*)d_in[11];
    const float* gW2 = (const float*)d_in[12];
    const float* gb2 = (const float*)d_in[13];
    float* out = (float*)d_out;

    // per-pair scratch: xfT+xfb+qkT+attnb+yTb+eb+Z = 4,952,064 B.
    const int chList[6] = {96, 48, 24, 12, 6, 3};
    int CH = 3;
    for (int i = 0; i < 6; ++i) {
        size_t need = 7868544ull + (size_t)chList[i] * 4952064ull;
        if (need <= ws_size) { CH = chList[i]; break; }
    }
    const int NCHUNK = 96 / CH;

    char* ws = (char*)d_ws;
    __hip_bfloat16* Wqkb = (__hip_bfloat16*)(ws + 0);          // 1,572,864 B
    __hip_bfloat16* Wvb  = (__hip_bfloat16*)(ws + 1572864);    // 6,291,456 B
    float* bqk = (float*)(ws + 7864320);
    float* wg  = (float*)(ws + 7867392);
    float* cpa = (float*)(ws + 7867776);
    float* cca = (float*)(ws + 7868160);
    __hip_bfloat16* xfT   = (__hip_bfloat16*)(ws + 7868544);
    __hip_bfloat16* xfb   = xfT   + (int64_t)CH * 393216;
    __hip_bfloat16* qkT   = xfb   + (int64_t)CH * 393216;
    __hip_bfloat16* attnb = qkT   + (int64_t)CH * 98304;
    __hip_bfloat16* yTb   = attnb + (int64_t)CH * 147456;
    __hip_bfloat16* eb    = yTb   + (int64_t)CH * 393216;
    float*          Zbuf  = (float*)(eb + (int64_t)CH * 1048576);

    gate_kernel<<<1, 768, 0, stream>>>(mod, gW1, gb1, gW2, gb2, gpa, gca, bq, bk,
                                       wg, cpa, cca, bqk);
    wcast_kernel<<<3840, 256, 0, stream>>>(Wq, Wk, Wv, Wqkb, Wvb);

    for (int ch = 0; ch < NCHUNK; ++ch) {
        const int pair0 = ch * CH;
        const int b0 = pair0 / kP;
        const float* xc   = x   + (int64_t)b0 * kCHW;
        float*       outc = out + (int64_t)b0 * kCHW;

        cast_tr_kernel<<<dim3(32, 3, CH), 256, 0, stream>>>(xc, xfb, xfT);
        zeroz_kernel<<<CH, 1024, 0, stream>>>(Zbuf);

        // qkT[n, 0:256] = xfT @ Wqk^T + bqk : M=384 N=256 K=1024
        mm_kernel<2><<<dim3(3, 2, CH), 256, 0, stream>>>(
            xfT, 3 * 393216, 393216, 1024,
            Wqkb, 0, 262144, 1024,
            qkT, 3 * 98304, 98304, 256,
            bqk, 256, 1024);
        // logits[n, m] = q @ k^T : M=384 N=384 K=128
        mm_kernel<0><<<dim3(3, 3, CH), 256, 0, stream>>>(
            qkT, 3 * 98304, 98304, 256,
            qkT + 128, 3 * 98304, 98304, 256,
            attnb, 3 * 147456, 147456, 384,
            nullptr, 0, 128);
        sm_pam<<<CH * (kN / 4), 256, 0, stream>>>(attnb, cpa + pair0, CH);
        // yT[m, c] = (cpa*attn) @ xfb^T : M=384 N=1024 K=384
        mm_kernel<0><<<dim3(3, 8, CH), 256, 0, stream>>>(
            attnb, 3 * 147456, 147456, 384,
            xfb, 3 * 393216, 393216, 384,
            yTb, 3 * 393216, 393216, 1024,
            nullptr, 0, 384);
        // eb = exp(-60 - xfb@xfb^T) (triangular, mirrored), Z = rowsums
        ecam_kernel<<<dim3(36, 1, CH), 256, 0, stream>>>(xfb, eb, Zbuf);
        // out = x*(1+w) + (cca/Z)*(Ep@xf) + Wv@(cpa*y) + cpa*bv : K=2048
        ep_cam_kernel<<<dim3(8, 3, CH), 256, 0, stream>>>(
            Wvb, yTb, eb, xfT, Zbuf, xc, outc,
            wg + pair0, cpa + pair0, cca + pair0, bv);
    }
}

// Round 8
// 540.621 us; speedup vs baseline: 1.0640x; 1.0640x over previous
//
#include <hip/hip_runtime.h>
#include <hip/hip_bf16.h>
#include <cstdint>

// ---------------- problem constants ----------------
constexpr int kB  = 32;
constexpr int kC  = 1024;
constexpr int kH  = 48;
constexpr int kW  = 24;
constexpr int kP  = 3;
constexpr int kPH = 16;
constexpr int kN  = kPH * kW;          // 384
constexpr int kHW = kH * kW;           // 1152
constexpr int64_t kCHW = (int64_t)kC * kHW;

typedef __attribute__((ext_vector_type(8))) short short8b;   // bf16x8 frag
typedef __attribute__((ext_vector_type(4))) float f32x4;

__device__ __forceinline__ void gl_lds16(const void* g, void* l) {
    __builtin_amdgcn_global_load_lds(
        (const __attribute__((address_space(1))) void*)g,
        (__attribute__((address_space(3))) void*)l, 16, 0, 0);
}

// XCD pair-locality swizzle (identity unless gridDim.z % 8 == 0).
__device__ __forceinline__ void swz_block(int& bx, int& by, int& bz) {
    const int gx = gridDim.x, gy = gridDim.y, gz = gridDim.z;
    if ((gz & 7) == 0) {
        const int tpp = gx * gy;
        const int L   = (blockIdx.z * gy + blockIdx.y) * gx + blockIdx.x;
        const int xcd = L & 7;
        const int idx = L >> 3;
        const int ppx = gz >> 3;
        const int pairL = idx / tpp;
        const int tile  = idx - pairL * tpp;
        bz = xcd * ppx + pairL;
        by = tile / gx;
        bx = tile - by * gx;
    } else {
        bx = blockIdx.x; by = blockIdx.y; bz = blockIdx.z;
    }
}

#define WAIT8()       asm volatile("s_waitcnt vmcnt(8)" ::: "memory")
#define WAIT0()       asm volatile("s_waitcnt vmcnt(0)" ::: "memory")
#define RAW_BARRIER() asm volatile("s_barrier" ::: "memory")
#define SFENCE()      __builtin_amdgcn_sched_barrier(0)

// ---------------- gate + bqk stack ----------------
__global__ void gate_kernel(const int* __restrict__ modality,
                            const float* __restrict__ gW1, const float* __restrict__ gb1,
                            const float* __restrict__ gW2, const float* __restrict__ gb2,
                            const float* __restrict__ gpa, const float* __restrict__ gca,
                            const float* __restrict__ bq, const float* __restrict__ bk,
                            float* __restrict__ wg, float* __restrict__ cpa,
                            float* __restrict__ cca, float* __restrict__ bqk)
{
    const int t = threadIdx.x;
    if (t < 768) {
        const int p = t >> 8, o = t & 255;
        bqk[t] = (o < 128) ? bq[p * 128 + o] : bk[p * 128 + (o - 128)];
    }
    if (t < kB * kP) {
        const int b = t / kP, p = t % kP;
        const float m = (float)modality[b];
        float acc = gb2[p];
        #pragma unroll
        for (int j = 0; j < 64; ++j) {
            float h = fmaxf(fmaf(m, gW1[j], gb1[j]), 0.0f);
            acc = fmaf(gW2[p * 64 + j], h, acc);
        }
        const float w = 1.0f / (1.0f + __expf(-acc));
        wg[t]  = w;
        cpa[t] = w * gpa[p];
        cca[t] = w * gca[p];
    }
}

// ---------------- weight precast fp32 -> bf16 ----------------
__global__ __launch_bounds__(256)
void wcast_kernel(const float* __restrict__ Wq, const float* __restrict__ Wk,
                  const float* __restrict__ Wv,
                  __hip_bfloat16* __restrict__ Wqkb, __hip_bfloat16* __restrict__ Wvb)
{
    const int64_t i = (int64_t)blockIdx.x * 256 + threadIdx.x;
    if (i < 196608) {
        const int64_t e = i * 4;
        const int p = (int)(e / 262144);
        const int rem = (int)(e % 262144);
        const int o = rem / 1024, c = rem % 1024;
        const float* s = (o < 128) ? (Wq + (int64_t)p * 131072 + (int64_t)o * 1024 + c)
                                   : (Wk + (int64_t)p * 131072 + (int64_t)(o - 128) * 1024 + c);
        float4 v = *(const float4*)s;
        __hip_bfloat16* d = Wqkb + e;
        d[0] = __float2bfloat16(v.x); d[1] = __float2bfloat16(v.y);
        d[2] = __float2bfloat16(v.z); d[3] = __float2bfloat16(v.w);
    } else if (i < 196608 + 786432) {
        const int64_t e = (i - 196608) * 4;
        float4 v = *(const float4*)(Wv + e);
        __hip_bfloat16* d = Wvb + e;
        d[0] = __float2bfloat16(v.x); d[1] = __float2bfloat16(v.y);
        d[2] = __float2bfloat16(v.z); d[3] = __float2bfloat16(v.w);
    }
}

// ---------------- Z zeroing (per chunk) ----------------
__global__ void zeroz_kernel(float* __restrict__ Z)
{
    Z[(int64_t)blockIdx.x * 1024 + threadIdx.x] = 0.0f;
}

// ---------------- per-chunk cast + transpose, vectorized (G13) -----------
__global__ __launch_bounds__(256)
void cast_tr_kernel(const float* __restrict__ x,  // + b0*kCHW
                    __hip_bfloat16* __restrict__ xfb,
                    __hip_bfloat16* __restrict__ xfT)
{
    int bx, by, bz;                 // grid (32, 3, CH)
    swz_block(bx, by, bz);
    const int j = bz;
    const int bb = j / kP, pp = j % kP;
    const float* src = x + (int64_t)bb * kCHW + pp * kN;
    const int c0 = bx * 32, n0 = by * 128;
    __shared__ float tile[32][129];
    const int tx = threadIdx.x & 31, ty = threadIdx.x >> 5;
    #pragma unroll
    for (int r = 0; r < 4; ++r) {
        const int cl = ty * 4 + r;
        const int c  = c0 + cl;
        float4 v = *(const float4*)(src + (int64_t)c * kHW + n0 + tx * 4);
        __hip_bfloat16 h0 = __float2bfloat16(v.x), h1 = __float2bfloat16(v.y);
        __hip_bfloat16 h2 = __float2bfloat16(v.z), h3 = __float2bfloat16(v.w);
        ushort4 hv;
        hv.x = *(ushort*)&h0; hv.y = *(ushort*)&h1;
        hv.z = *(ushort*)&h2; hv.w = *(ushort*)&h3;
        *(ushort4*)((ushort*)xfb + (int64_t)j * 393216 + (int64_t)c * kN + n0 + tx * 4) = hv;
        tile[cl][tx * 4 + 0] = v.x; tile[cl][tx * 4 + 1] = v.y;
        tile[cl][tx * 4 + 2] = v.z; tile[cl][tx * 4 + 3] = v.w;
    }
    __syncthreads();
    const int cc = (threadIdx.x & 15) * 2;
    const int nr = threadIdx.x >> 4;          // 0..15
    #pragma unroll
    for (int r = 0; r < 8; ++r) {
        const int nl = r * 16 + nr;
        __hip_bfloat16 h0 = __float2bfloat16(tile[cc][nl]);
        __hip_bfloat16 h1 = __float2bfloat16(tile[cc + 1][nl]);
        ushort2 h2; h2.x = *(ushort*)&h0; h2.y = *(ushort*)&h1;
        *(ushort2*)((ushort*)xfT + (int64_t)j * 393216 + (int64_t)(n0 + nl) * kC + c0 + cc) = h2;
    }
}

// ---------------- bf16 MFMA GEMM, 128x128 tile, BK=64, counted-vmcnt dbuf -
// r0-proven form for the SHORT-K mid GEMMs (K=128..1024): dbuf + WAIT8.
// (r7's single-buffer conversion of these cost +43 us — short K loops
// don't amortize the full-drain prologue; reverted.)
template<int BIAS>
__global__ __launch_bounds__(256, 2)
void mm_kernel(const __hip_bfloat16* __restrict__ A0, int64_t aSB, int64_t aSP, int lda,
               const __hip_bfloat16* __restrict__ B0, int64_t bSB, int64_t bSP, int ldb,
               __hip_bfloat16* __restrict__ C0, int64_t cSB, int64_t cSP, int ldc,
               const float* __restrict__ bias0, int biasSP, int K)
{
    __shared__ char lds[65536];   // 2 x (16KB A + 16KB B)

    int bx, by, bz;
    swz_block(bx, by, bz);
    const int j = bz, bb = j / kP, pp = j % kP;
    const char* Ab = (const char*)(A0 + (int64_t)bb * aSB + (int64_t)pp * aSP);
    const char* Bb = (const char*)(B0 + (int64_t)bb * bSB + (int64_t)pp * bSP);
    const int m0 = bx * 128, n0 = by * 128;
    const int t = threadIdx.x, lane = t & 63, wv = t >> 6;
    const int wm = (wv & 1) * 64, wn = (wv >> 1) * 64;
    const size_t ldab = (size_t)lda * 2, ldbb = (size_t)ldb * 2;

    const int rr   = wv * 8 + (lane >> 3);
    const int gsrc = ((lane & 7) ^ (lane >> 3)) * 16;
    const int lrow = (wv * 8 + (lane >> 3)) * 128 + (lane & 7) * 16;

    auto STAGE = [&](int buf, int k0) {
        const char* Asrc = Ab + (size_t)(m0 + rr) * ldab + (size_t)k0 * 2 + gsrc;
        const char* Bsrc = Bb + (size_t)(n0 + rr) * ldbb + (size_t)k0 * 2 + gsrc;
        char* As = lds + buf * 32768;
        char* Bs = As + 16384;
        #pragma unroll
        for (int i = 0; i < 4; ++i) {
            gl_lds16(Asrc + (size_t)i * 32 * ldab, As + i * 4096 + lrow);
            gl_lds16(Bsrc + (size_t)i * 32 * ldbb, Bs + i * 4096 + lrow);
        }
    };

    f32x4 acc[4][4];
    #pragma unroll
    for (int a = 0; a < 4; ++a)
        #pragma unroll
        for (int b = 0; b < 4; ++b) acc[a][b] = (f32x4){0.f, 0.f, 0.f, 0.f};

    const int nk = K >> 6;
    STAGE(0, 0);
    int cur = 0;
    for (int k = 0; k < nk; ++k) {
        if (k + 1 < nk) { STAGE(cur ^ 1, (k + 1) << 6); WAIT8(); }
        else            { WAIT0(); }
        SFENCE();
        RAW_BARRIER();
        const char* As = lds + cur * 32768;
        const char* Bs = As + 16384;
        #pragma unroll
        for (int kk = 0; kk < 2; ++kk) {
            const int gpos = ((kk * 4 + (lane >> 4)) ^ (lane & 7)) * 16;
            short8b af[4], bf[4];
            #pragma unroll
            for (int f = 0; f < 4; ++f) {
                af[f] = *(const short8b*)(As + (wm + f * 16 + (lane & 15)) * 128 + gpos);
                bf[f] = *(const short8b*)(Bs + (wn + f * 16 + (lane & 15)) * 128 + gpos);
            }
            #pragma unroll
            for (int fm = 0; fm < 4; ++fm)
                #pragma unroll
                for (int fn = 0; fn < 4; ++fn)
                    acc[fm][fn] = __builtin_amdgcn_mfma_f32_16x16x32_bf16(
                        af[fm], bf[fn], acc[fm][fn], 0, 0, 0);
        }
        RAW_BARRIER();
        cur ^= 1;
    }

    __hip_bfloat16* Cm = C0 + (int64_t)bb * cSB + (int64_t)pp * cSP;
    #pragma unroll
    for (int fn = 0; fn < 4; ++fn) {
        const int col = n0 + wn + fn * 16 + (lane & 15);
        const float cb = (BIAS == 2) ? bias0[pp * biasSP + col] : 0.0f;
        #pragma unroll
        for (int fm = 0; fm < 4; ++fm)
            #pragma unroll
            for (int jr = 0; jr < 4; ++jr) {
                const int row = m0 + wm + fm * 16 + (lane >> 4) * 4 + jr;
                Cm[(int64_t)row * ldc + col] = __float2bfloat16(acc[fm][fn][jr] + cb);
            }
    }
}

// ---------------- triangular e-GEMM with fused exp + Z atomics ------------
// r0-proven dbuf form (short K=384: 6 steps).
__global__ __launch_bounds__(256, 2)
void ecam_kernel(const __hip_bfloat16* __restrict__ xfb,   // [CH][1024][384]
                 __hip_bfloat16* __restrict__ eb,          // [CH][1024][1024]
                 float* __restrict__ Z)                    // [CH][1024]
{
    __shared__ char lds[65536];

    int bx, by, bz;                 // grid (36, 1, CH); bx = triangle index
    swz_block(bx, by, bz);
    const int j = bz;
    int bi = 0;
    while ((bi + 1) * (bi + 2) / 2 <= bx) ++bi;   // <= 7 iters
    const int bj = bx - bi * (bi + 1) / 2;        // bi >= bj
    const char* Ab = (const char*)(xfb + (int64_t)j * 393216);
    const int m0 = bi * 128, n0 = bj * 128;
    const int t = threadIdx.x, lane = t & 63, wv = t >> 6;
    const int wm = (wv & 1) * 64, wn = (wv >> 1) * 64;
    constexpr size_t ldab = 768;   // 384 bf16

    const int rr   = wv * 8 + (lane >> 3);
    const int gsrc = ((lane & 7) ^ (lane >> 3)) * 16;
    const int lrow = (wv * 8 + (lane >> 3)) * 128 + (lane & 7) * 16;

    auto STAGE = [&](int buf, int k0) {
        const char* Asrc = Ab + (size_t)(m0 + rr) * ldab + (size_t)k0 * 2 + gsrc;
        const char* Bsrc = Ab + (size_t)(n0 + rr) * ldab + (size_t)k0 * 2 + gsrc;
        char* As = lds + buf * 32768;
        char* Bs = As + 16384;
        #pragma unroll
        for (int i = 0; i < 4; ++i) {
            gl_lds16(Asrc + (size_t)i * 32 * ldab, As + i * 4096 + lrow);
            gl_lds16(Bsrc + (size_t)i * 32 * ldab, Bs + i * 4096 + lrow);
        }
    };

    f32x4 acc[4][4];
    #pragma unroll
    for (int a = 0; a < 4; ++a)
        #pragma unroll
        for (int b = 0; b < 4; ++b) acc[a][b] = (f32x4){0.f, 0.f, 0.f, 0.f};

    STAGE(0, 0);
    int cur = 0;
    for (int k = 0; k < 6; ++k) {
        if (k + 1 < 6) { STAGE(cur ^ 1, (k + 1) << 6); WAIT8(); }
        else           { WAIT0(); }
        SFENCE();
        RAW_BARRIER();
        const char* As = lds + cur * 32768;
        const char* Bs = As + 16384;
        #pragma unroll
        for (int kk = 0; kk < 2; ++kk) {
            const int gpos = ((kk * 4 + (lane >> 4)) ^ (lane & 7)) * 16;
            short8b af[4], bf[4];
            #pragma unroll
            for (int f = 0; f < 4; ++f) {
                af[f] = *(const short8b*)(As + (wm + f * 16 + (lane & 15)) * 128 + gpos);
                bf[f] = *(const short8b*)(Bs + (wn + f * 16 + (lane & 15)) * 128 + gpos);
            }
            #pragma unroll
            for (int fm = 0; fm < 4; ++fm)
                #pragma unroll
                for (int fn = 0; fn < 4; ++fn)
                    acc[fm][fn] = __builtin_amdgcn_mfma_f32_16x16x32_bf16(
                        af[fm], bf[fn], acc[fm][fn], 0, 0, 0);
        }
        RAW_BARRIER();
        cur ^= 1;
    }

    // transform acc -> p = exp(-60 - S) in place (literal indices only)
    #pragma unroll
    for (int fm = 0; fm < 4; ++fm)
        #pragma unroll
        for (int fn = 0; fn < 4; ++fn)
            #pragma unroll
            for (int jr = 0; jr < 4; ++jr)
                acc[fm][fn][jr] = __expf(-60.f - acc[fm][fn][jr]);

    __hip_bfloat16* Cm = eb + (int64_t)j * 1048576;
    float* Zp = Z + (int64_t)j * 1024;

    // normal tile write + row sums -> Z[row]
    #pragma unroll
    for (int fm = 0; fm < 4; ++fm)
        #pragma unroll
        for (int jr = 0; jr < 4; ++jr) {
            const int row = m0 + wm + fm * 16 + (lane >> 4) * 4 + jr;
            float v = 0.f;
            #pragma unroll
            for (int fn = 0; fn < 4; ++fn) {
                const int col = n0 + wn + fn * 16 + (lane & 15);
                Cm[(int64_t)row * 1024 + col] = __float2bfloat16(acc[fm][fn][jr]);
                v += acc[fm][fn][jr];
            }
            v += __shfl_xor(v, 1);
            v += __shfl_xor(v, 2);
            v += __shfl_xor(v, 4);
            v += __shfl_xor(v, 8);
            if ((lane & 15) == 0) atomicAdd(Zp + row, v);
        }

    if (bi != bj) {
        // mirrored tile write: Cm[col][row0..row0+3] as one 8B packed store
        #pragma unroll
        for (int fn = 0; fn < 4; ++fn) {
            const int col = n0 + wn + fn * 16 + (lane & 15);
            float v2 = 0.f;
            #pragma unroll
            for (int fm = 0; fm < 4; ++fm) {
                const int row0 = m0 + wm + fm * 16 + (lane >> 4) * 4;
                __hip_bfloat16 h0 = __float2bfloat16(acc[fm][fn][0]);
                __hip_bfloat16 h1 = __float2bfloat16(acc[fm][fn][1]);
                __hip_bfloat16 h2 = __float2bfloat16(acc[fm][fn][2]);
                __hip_bfloat16 h3 = __float2bfloat16(acc[fm][fn][3]);
                ushort4 w4;
                w4.x = *(ushort*)&h0; w4.y = *(ushort*)&h1;
                w4.z = *(ushort*)&h2; w4.w = *(ushort*)&h3;
                *(ushort4*)((ushort*)Cm + (int64_t)col * 1024 + row0) = w4;
                v2 += (acc[fm][fn][0] + acc[fm][fn][1]) +
                      (acc[fm][fn][2] + acc[fm][fn][3]);
            }
            // column sums -> Z[col] (mirror block's row sums)
            v2 += __shfl_xor(v2, 16);
            v2 += __shfl_xor(v2, 32);
            if ((lane >> 4) == 0) atomicAdd(Zp + col, v2);
        }
    }
}

// ---------------- merged final GEMM (K = 2*1024), m97-style ---------------
// r7-proven best form (233 us @CH=96): 128x128 tile, 4 waves, BK=64,
// SINGLE 32KB buffer, vmcnt(0) drain, 2 barriers, 4 blocks/CU. Long K
// (32 steps) amortizes the drain; block-level TLP hides it (m114).
__global__ __launch_bounds__(256, 4)
void ep_cam_kernel(const __hip_bfloat16* __restrict__ Wvb,  // [P][1024][1024]
                   const __hip_bfloat16* __restrict__ yTb,  // [CH][384][1024]
                   const __hip_bfloat16* __restrict__ eb,   // [CH][1024][1024]
                   const __hip_bfloat16* __restrict__ xfT,  // [CH][384][1024]
                   const float* __restrict__ Z,             // [CH][1024]
                   const float* __restrict__ x,             // + b0*kCHW
                   float* __restrict__ out,                 // + b0*kCHW
                   const float* __restrict__ wg,            // + pair0
                   const float* __restrict__ cpa,           // + pair0
                   const float* __restrict__ cca,           // + pair0
                   const float* __restrict__ bv)            // [P][1024]
{
    __shared__ char lds[32768];     // 16KB A + 16KB B, single buffer

    int bx, by, bz;                 // grid (8, 3, CH)
    swz_block(bx, by, bz);
    const int j = bz, bb = j / kP, pp = j % kP;
    const int m0 = bx * 128, n0 = by * 128;
    const int t = threadIdx.x, lane = t & 63, wv = t >> 6;
    const int wm = (wv & 1) * 64, wn = (wv >> 1) * 64;

    const int rr   = wv * 8 + (lane >> 3);
    const int gsrc = ((lane & 7) ^ (lane >> 3)) * 16;
    const int lrow = (wv * 8 + (lane >> 3)) * 128 + (lane & 7) * 16;

    const char* AbW = (const char*)(Wvb + (int64_t)pp * 1048576);
    const char* AbE = (const char*)(eb  + (int64_t)j  * 1048576);
    const char* BbY = (const char*)(yTb + (int64_t)j * 393216);
    const char* BbX = (const char*)(xfT + (int64_t)j * 393216);

    auto STAGE = [&](int k) {        // 8 gl_lds16 per lane
        const char* A = (k < 16) ? AbE : AbW;    // half 0 = E, half 1 = Wv
        const char* B = (k < 16) ? BbX : BbY;
        const size_t k0b = (size_t)(k & 15) * 128;  // 64 bf16 = 128B per step
        const char* Asrc = A + (size_t)(m0 + rr) * 2048 + k0b + gsrc;
        const char* Bsrc = B + (size_t)(n0 + rr) * 2048 + k0b + gsrc;
        char* As = lds;
        char* Bs = As + 16384;
        #pragma unroll
        for (int i = 0; i < 4; ++i) {
            gl_lds16(Asrc + (size_t)i * 32 * 2048, As + i * 4096 + lrow);
            gl_lds16(Bsrc + (size_t)i * 32 * 2048, Bs + i * 4096 + lrow);
        }
    };

    // preload row scales so the mid-loop rescale is pure VALU
    const float cfc = cca[j];
    const float* Zp = Z + (int64_t)j * 1024;
    float zsc[4][4];
    #pragma unroll
    for (int fm = 0; fm < 4; ++fm)
        #pragma unroll
        for (int jr = 0; jr < 4; ++jr) {
            const int row = m0 + wm + fm * 16 + (lane >> 4) * 4 + jr;
            zsc[fm][jr] = cfc / Zp[row];
        }

    f32x4 acc[4][4];
    #pragma unroll
    for (int a = 0; a < 4; ++a)
        #pragma unroll
        for (int b = 0; b < 4; ++b) acc[a][b] = (f32x4){0.f, 0.f, 0.f, 0.f};

    #pragma unroll 1
    for (int k = 0; k < 32; ++k) {
        STAGE(k);
        WAIT0();
        SFENCE();
        RAW_BARRIER();
        if (k == 16) {               // fold CAM row-scale into the C operand
            #pragma unroll
            for (int fm = 0; fm < 4; ++fm)
                #pragma unroll
                for (int jr = 0; jr < 4; ++jr) {
                    const float zs = zsc[fm][jr];
                    #pragma unroll
                    for (int fn = 0; fn < 4; ++fn) acc[fm][fn][jr] *= zs;
                }
        }
        const char* As = lds;
        const char* Bs = As + 16384;
        #pragma unroll
        for (int kk = 0; kk < 2; ++kk) {
            const int gpos = ((kk * 4 + (lane >> 4)) ^ (lane & 7)) * 16;
            short8b af[4], bf[4];
            #pragma unroll
            for (int f = 0; f < 4; ++f) {
                af[f] = *(const short8b*)(As + (wm + f * 16 + (lane & 15)) * 128 + gpos);
                bf[f] = *(const short8b*)(Bs + (wn + f * 16 + (lane & 15)) * 128 + gpos);
            }
            #pragma unroll
            for (int fm = 0; fm < 4; ++fm)
                #pragma unroll
                for (int fn = 0; fn < 4; ++fn)
                    acc[fm][fn] = __builtin_amdgcn_mfma_f32_16x16x32_bf16(
                        af[fm], bf[fn], acc[fm][fn], 0, 0, 0);
        }
        RAW_BARRIER();
    }

    const float gsc = 1.0f + wg[j];
    const float cfp = cpa[j];
    const float* Xm = x   + (int64_t)bb * kCHW + pp * kN;
    float*       Om = out + (int64_t)bb * kCHW + pp * kN;
    #pragma unroll
    for (int fm = 0; fm < 4; ++fm)
        #pragma unroll
        for (int jr = 0; jr < 4; ++jr) {
            const int row = m0 + wm + fm * 16 + (lane >> 4) * 4 + jr;
            const float rb = cfp * bv[pp * 1024 + row];
            #pragma unroll
            for (int fn = 0; fn < 4; ++fn) {
                const int col = n0 + wn + fn * 16 + (lane & 15);
                const int64_t off = (int64_t)row * kHW + col;
                Om[off] = fmaf(gsc, Xm[off], acc[fm][fn][jr] + rb);
            }
        }
}

// ---------------- PAM softmax: 4 rows per 256-thr block ------------------
__global__ __launch_bounds__(256) void sm_pam(__hip_bfloat16* __restrict__ buf,
                                              const float* __restrict__ scale,
                                              int chPairs)
{
    const int R = blockIdx.x * 4 + (threadIdx.x >> 6);   // global row id
    const int pair = R / kN, row = R % kN;
    __hip_bfloat16* rp = buf + (int64_t)pair * (kN * kN) + (int64_t)row * kN;
    const int t = threadIdx.x & 63;
    float v[6];
    float mx = -3.402823466e38f;
    #pragma unroll
    for (int r = 0; r < 6; ++r) {
        v[r] = __bfloat162float(rp[t + 64 * r]);
        mx = fmaxf(mx, v[r]);
    }
    #pragma unroll
    for (int off = 32; off > 0; off >>= 1) mx = fmaxf(mx, __shfl_xor(mx, off));
    float s = 0.0f;
    #pragma unroll
    for (int r = 0; r < 6; ++r) { v[r] = __expf(v[r] - mx); s += v[r]; }
    #pragma unroll
    for (int off = 32; off > 0; off >>= 1) s += __shfl_xor(s, off);
    const float inv = scale[pair] / s;
    #pragma unroll
    for (int r = 0; r < 6; ++r) rp[t + 64 * r] = __float2bfloat16(v[r] * inv);
}

// ---------------- launch ----------------
extern "C" void kernel_launch(void* const* d_in, const int* in_sizes, int n_in,
                              void* d_out, int out_size, void* d_ws, size_t ws_size,
                              hipStream_t stream)
{
    const float* x   = (const float*)d_in[0];
    const int*   mod = (const int*)d_in[1];
    const float* Wq  = (const float*)d_in[2];
    const float* bq  = (const float*)d_in[3];
    const float* Wk  = (const float*)d_in[4];
    const float* bk  = (const float*)d_in[5];
    const float* Wv  = (const float*)d_in[6];
    const float* bv  = (const float*)d_in[7];
    const float* gpa = (const float*)d_in[8];
    const float* gca = (const float*)d_in[9];
    const float* gW1 = (const float*)d_in[10];
    const float* gb1 = (const float*)d_in[11];
    const float* gW2 = (const float*)d_in[12];
    const float* gb2 = (const float*)d_in[13];
    float* out = (float*)d_out;

    // per-pair scratch: xfT+xfb+qkT+attnb+yTb+eb+Z = 4,952,064 B.
    // CH=48 (NOT 96): per-chunk working set ~185 MB fits the 256 MB L3,
    // keeping ecam's eb writes L3-resident for ep_cam's reads. CH=96
    // (~370 MB) thrashed L3: non-ep_cam time 282 us (r0, CH=48) vs
    // 295-300 us (r1/r2/r5, CH=96) at identical kernels.
    const int chList[5] = {48, 24, 12, 6, 3};
    int CH = 3;
    for (int i = 0; i < 5; ++i) {
        size_t need = 7868544ull + (size_t)chList[i] * 4952064ull;
        if (need <= ws_size) { CH = chList[i]; break; }
    }
    const int NCHUNK = 96 / CH;

    char* ws = (char*)d_ws;
    __hip_bfloat16* Wqkb = (__hip_bfloat16*)(ws + 0);          // 1,572,864 B
    __hip_bfloat16* Wvb  = (__hip_bfloat16*)(ws + 1572864);    // 6,291,456 B
    float* bqk = (float*)(ws + 7864320);
    float* wg  = (float*)(ws + 7867392);
    float* cpa = (float*)(ws + 7867776);
    float* cca = (float*)(ws + 7868160);
    __hip_bfloat16* xfT   = (__hip_bfloat16*)(ws + 7868544);
    __hip_bfloat16* xfb   = xfT   + (int64_t)CH * 393216;
    __hip_bfloat16* qkT   = xfb   + (int64_t)CH * 393216;
    __hip_bfloat16* attnb = qkT   + (int64_t)CH * 98304;
    __hip_bfloat16* yTb   = attnb + (int64_t)CH * 147456;
    __hip_bfloat16* eb    = yTb   + (int64_t)CH * 393216;
    float*          Zbuf  = (float*)(eb + (int64_t)CH * 1048576);

    gate_kernel<<<1, 768, 0, stream>>>(mod, gW1, gb1, gW2, gb2, gpa, gca, bq, bk,
                                       wg, cpa, cca, bqk);
    wcast_kernel<<<3840, 256, 0, stream>>>(Wq, Wk, Wv, Wqkb, Wvb);

    for (int ch = 0; ch < NCHUNK; ++ch) {
        const int pair0 = ch * CH;
        const int b0 = pair0 / kP;
        const float* xc   = x   + (int64_t)b0 * kCHW;
        float*       outc = out + (int64_t)b0 * kCHW;

        cast_tr_kernel<<<dim3(32, 3, CH), 256, 0, stream>>>(xc, xfb, xfT);
        zeroz_kernel<<<CH, 1024, 0, stream>>>(Zbuf);

        // qkT[n, 0:256] = xfT @ Wqk^T + bqk : M=384 N=256 K=1024
        mm_kernel<2><<<dim3(3, 2, CH), 256, 0, stream>>>(
            xfT, 3 * 393216, 393216, 1024,
            Wqkb, 0, 262144, 1024,
            qkT, 3 * 98304, 98304, 256,
            bqk, 256, 1024);
        // logits[n, m] = q @ k^T : M=384 N=384 K=128
        mm_kernel<0><<<dim3(3, 3, CH), 256, 0, stream>>>(
            qkT, 3 * 98304, 98304, 256,
            qkT + 128, 3 * 98304, 98304, 256,
            attnb, 3 * 147456, 147456, 384,
            nullptr, 0, 128);
        sm_pam<<<CH * (kN / 4), 256, 0, stream>>>(attnb, cpa + pair0, CH);
        // yT[m, c] = (cpa*attn) @ xfb^T : M=384 N=1024 K=384
        mm_kernel<0><<<dim3(3, 8, CH), 256, 0, stream>>>(
            attnb, 3 * 147456, 147456, 384,
            xfb, 3 * 393216, 393216, 384,
            yTb, 3 * 393216, 393216, 1024,
            nullptr, 0, 384);
        // eb = exp(-60 - xfb@xfb^T) (triangular, mirrored), Z = rowsums
        ecam_kernel<<<dim3(36, 1, CH), 256, 0, stream>>>(xfb, eb, Zbuf);
        // out = x*(1+w) + (cca/Z)*(Ep@xf) + Wv@(cpa*y) + cpa*bv : K=2048
        ep_cam_kernel<<<dim3(8, 3, CH), 256, 0, stream>>>(
            Wvb, yTb, eb, xfT, Zbuf, xc, outc,
            wg + pair0, cpa + pair0, cca + pair0, bv);
    }
}